// Round 7
// baseline (1452.396 us; speedup 1.0000x reference)
//
#include <hip/hip_runtime.h>

#define NH 8
#define DH 16
#define OD 128
#define NCH 256     // scatter chunks (blocks)
#define NPB 64      // nodes per bin
#define ECAP 1536   // max edges per bin held in LDS (mean ~1088)

typedef __attribute__((ext_vector_type(8))) short bf16x8;
typedef __attribute__((ext_vector_type(4))) float f32x4;

__device__ inline unsigned int f2bf(float f) {
    unsigned int u = __float_as_uint(f);
    return (u + 0x7fffu + ((u >> 16) & 1u)) >> 16;
}

// ---- binned counting sort ----------------------------------------------

// count matrix cnt[bin * NCH + chunk]
__global__ __launch_bounds__(256) void binhist_kernel(const int2* __restrict__ el,
                                                      int* __restrict__ cnt,
                                                      int E, int total, int CH, int NB) {
    __shared__ int lh[2048];
    int t = threadIdx.x, c = blockIdx.x;
    for (int i = t; i < NB; i += 256) lh[i] = 0;
    __syncthreads();
    int beg = c * CH, end = min(total, beg + CH);
    for (int i = beg + t; i < end; i += 256) {
        int dst = (i < E) ? el[i].y : (i - E);
        atomicAdd(&lh[dst >> 6], 1);
    }
    __syncthreads();
    for (int i = t; i < NB; i += 256) cnt[i * NCH + c] = lh[i];
}

__global__ __launch_bounds__(1024) void scan1_kernel(const int* __restrict__ counts,
                                                     int* __restrict__ offsets,
                                                     int* __restrict__ bsums, int n) {
    __shared__ int tmp[1024];
    int t = threadIdx.x;
    int gid = blockIdx.x * 1024 + t;
    int v = (gid < n) ? counts[gid] : 0;
    tmp[t] = v;
    __syncthreads();
    int val = v;
    for (int off = 1; off < 1024; off <<= 1) {
        int add = (t >= off) ? tmp[t - off] : 0;
        __syncthreads();
        val += add;
        tmp[t] = val;
        __syncthreads();
    }
    if (gid < n) offsets[gid] = val - v;
    if (t == 1023) bsums[blockIdx.x] = val;
}

__global__ __launch_bounds__(1024) void scan2_kernel(int* __restrict__ bsums, int nb) {
    __shared__ int tmp[1024];
    int t = threadIdx.x;
    int v = (t < nb) ? bsums[t] : 0;
    tmp[t] = v;
    __syncthreads();
    int val = v;
    for (int off = 1; off < 1024; off <<= 1) {
        int add = (t >= off) ? tmp[t - off] : 0;
        __syncthreads();
        val += add;
        tmp[t] = val;
        __syncthreads();
    }
    if (t < nb) bsums[t] = val - v;
}

__global__ __launch_bounds__(1024) void scan3b_kernel(int* __restrict__ S,
                                                      const int* __restrict__ bsums,
                                                      const int* __restrict__ cnt, int n) {
    int gid = blockIdx.x * 1024 + threadIdx.x;
    if (gid < n) {
        int o = S[gid] + bsums[gid >> 10];
        S[gid] = o;
        if (gid == n - 1) S[n] = o + cnt[gid];
    }
}

// scatter edges into bin-contiguous, chunk-sequential regions.
// payload: word0 = src | (dstLocal << 17), word1 = edge weight bits
__global__ __launch_bounds__(256) void binscatter_kernel(const int2* __restrict__ el,
                                                         const float* __restrict__ ew,
                                                         const int* __restrict__ S,
                                                         int2* __restrict__ binned,
                                                         int E, int total, int CH, int NB) {
    __shared__ int lcur[2048];
    int t = threadIdx.x, c = blockIdx.x;
    for (int i = t; i < NB; i += 256) lcur[i] = S[i * NCH + c];
    __syncthreads();
    int beg = c * CH, end = min(total, beg + CH);
    for (int i = beg + t; i < end; i += 256) {
        int src, dst; float w;
        if (i < E) { int2 e = el[i]; src = e.x; dst = e.y; w = ew[i]; }
        else       { src = dst = i - E; w = 1.0f; }
        int b = dst >> 6;
        int pos = atomicAdd(&lcur[b], 1);
        binned[pos] = make_int2(src | ((dst & 63) << 17), __float_as_int(w));
    }
}

// one block per bin: LDS counting sort by SRC bucket (src>>9) for gather locality
__global__ __launch_bounds__(256) void binsort_kernel(const int2* __restrict__ binned,
                                                      const int* __restrict__ S,
                                                      int2* __restrict__ sedge,
                                                      int NB, int total) {
    __shared__ int2 eb[ECAP];
    __shared__ int lh[256];
    __shared__ int cu[256];
    int b = blockIdx.x, t = threadIdx.x;
    int base = S[b * NCH];
    int endb = S[(b + 1) * NCH];
    int cnt = min(endb - base, ECAP);

    if (t < 256) lh[t] = 0;
    __syncthreads();
    for (int i = t; i < cnt; i += 256) {
        int2 e = binned[base + i];
        eb[i] = e;
        atomicAdd(&lh[(e.x & 0x1FFFF) >> 9], 1);
    }
    __syncthreads();
    // exclusive scan of lh[0..256) by wave 0 (4 counters per lane)
    if (t < 64) {
        int loc[4]; int s = 0;
#pragma unroll
        for (int j = 0; j < 4; ++j) { loc[j] = lh[t * 4 + j]; s += loc[j]; }
        int inc = s;
        for (int d = 1; d < 64; d <<= 1) {
            int o = __shfl_up(inc, d, 64);
            if (t >= d) inc += o;
        }
        int ex = inc - s;
#pragma unroll
        for (int j = 0; j < 4; ++j) { cu[t * 4 + j] = ex; ex += loc[j]; }
    }
    __syncthreads();
    for (int i = t; i < cnt; i += 256) {
        int2 e = eb[i];
        int k = (e.x & 0x1FFFF) >> 9;
        int pos = atomicAdd(&cu[k], 1);
        sedge[base + pos] = e;   // keep dstLocal in payload
    }
}

// ---- MFMA bf16 GEMM: hidden = x@W + b ----------------------------------
__global__ __launch_bounds__(256) void gemm_proj_kernel(
        const float* __restrict__ x, const float* __restrict__ W,
        const float* __restrict__ b, const float* __restrict__ query,
        unsigned short* __restrict__ hbu, float* __restrict__ ain,
        float* __restrict__ aout, int N) {
    __shared__ unsigned short xs[64 * 136];
    __shared__ unsigned short wt[128 * 136];
    int t = threadIdx.x;
    int row0 = blockIdx.x * 64;

    {
        const float4* x4 = (const float4*)x;
#pragma unroll
        for (int i = 0; i < 8; ++i) {
            int f = t + i * 256;
            int row = f >> 5, c4 = f & 31;
            int gr = row0 + row;
            if (gr >= N) gr = N - 1;
            float4 v = x4[(size_t)gr * 32 + c4];
            unsigned int u0 = f2bf(v.x) | (f2bf(v.y) << 16);
            unsigned int u1 = f2bf(v.z) | (f2bf(v.w) << 16);
            *(uint2*)&xs[row * 136 + 4 * c4] = make_uint2(u0, u1);
        }
    }
    {
        const float4* W4 = (const float4*)W;
#pragma unroll
        for (int i = 0; i < 16; ++i) {
            int f = t + i * 256;
            int k = f & 127, c4 = f >> 7;
            float4 v = W4[k * 32 + c4];
            wt[(4 * c4 + 0) * 136 + k] = (unsigned short)f2bf(v.x);
            wt[(4 * c4 + 1) * 136 + k] = (unsigned short)f2bf(v.y);
            wt[(4 * c4 + 2) * 136 + k] = (unsigned short)f2bf(v.z);
            wt[(4 * c4 + 3) * 136 + k] = (unsigned short)f2bf(v.w);
        }
    }
    __syncthreads();

    int lane = t & 63, wv = t >> 6;
    int d = lane & 15, g = lane >> 4;
    int tbase = wv * 16;

    bf16x8 af[4];
#pragma unroll
    for (int s = 0; s < 4; ++s)
        af[s] = *(bf16x8*)&xs[(tbase + d) * 136 + s * 32 + g * 8];

    f32x4 acc[8];
#pragma unroll
    for (int c = 0; c < 8; ++c) acc[c] = (f32x4){0.f, 0.f, 0.f, 0.f};

#pragma unroll
    for (int c = 0; c < 8; ++c) {
#pragma unroll
        for (int s = 0; s < 4; ++s) {
            bf16x8 bf = *(bf16x8*)&wt[(d + 16 * c) * 136 + s * 32 + g * 8];
            acc[c] = __builtin_amdgcn_mfma_f32_16x16x32_bf16(af[s], bf, acc[c], 0, 0, 0);
        }
    }

    int rbase = row0 + tbase + g * 4;
#pragma unroll
    for (int c = 0; c < 8; ++c) {
        float bc = b[d + 16 * c];
        float2 q2 = *(const float2*)(query + c * 2 * DH + 2 * d);
#pragma unroll
        for (int j = 0; j < 4; ++j) {
            float v = acc[c][j] + bc;
            int row = rbase + j;
            if (row < N) hbu[(size_t)row * OD + d + 16 * c] = (unsigned short)f2bf(v);
            float pin = q2.x * v, pout = q2.y * v;
#pragma unroll
            for (int m = 1; m < 16; m <<= 1) {
                pin  += __shfl_xor(pin, m, 64);
                pout += __shfl_xor(pout, m, 64);
            }
            if (d == 0 && row < N) {
                ain[row * NH + c] = pin;
                aout[row * NH + c] = pout;
            }
        }
    }
}

// ---- aggregate: one block per 64-node bin, LDS accumulator --------------
// phase1: lane (h=l>>3, s=l&7) computes att for edge wb+s, head h;
//         LDS-atomics into ssum; att published via per-wave LDS buffer.
// phase2: lane owns dims 2l,2l+1; ds_add_f32 into accE/accO[dl][l].
__global__ __launch_bounds__(256) void aggregate_kernel(
        const int* __restrict__ S, const int2* __restrict__ sedge,
        const float* __restrict__ ain, const float* __restrict__ aout,
        const unsigned int* __restrict__ hb, float* __restrict__ out,
        int N, int NB) {
    __shared__ float accE[NPB * 64];   // 16 KB, even dims
    __shared__ float accO[NPB * 64];   // 16 KB, odd dims
    __shared__ float ssumL[NPB * NH];  // 2 KB
    __shared__ float aoutL[NPB * NH];  // 2 KB
    __shared__ int   cntL[NPB];
    __shared__ float attbuf[4][64];
    __shared__ int   srcbuf[4][8];
    __shared__ int   dlbuf[4][8];

    int b = blockIdx.x, t = threadIdx.x;
    int base = S[b * NCH], end = S[(b + 1) * NCH];
    int node0 = b * NPB;

    {
        float4* a4 = (float4*)accE;
        for (int i = t; i < NPB * 64 / 4; i += 256) a4[i] = make_float4(0, 0, 0, 0);
        float4* b4 = (float4*)accO;
        for (int i = t; i < NPB * 64 / 4; i += 256) b4[i] = make_float4(0, 0, 0, 0);
        for (int i = t; i < NPB * NH; i += 256) ssumL[i] = 0.0f;
        if (t < NPB) cntL[t] = 0;
        // preload aout rows for this bin (NPB*NH floats = 128 float4)
        if (t < NPB * NH / 4) {
            int node = node0 + (t * 4) / NH;
            float4 v = make_float4(0, 0, 0, 0);
            if (node < N) v = ((const float4*)aout)[(size_t)node0 * 2 + t];
            ((float4*)aoutL)[t] = v;
        }
    }
    __syncthreads();

    int lane = t & 63, wv = t >> 6;
    int h = lane >> 3, s = lane & 7;

    for (int wb = base + wv * 8; wb < end; wb += 32) {
        int idx = wb + s;
        float att = 0.0f;
        if (idx < end) {
            int2 e = sedge[idx];
            int src = e.x & 0x1FFFF, dl = e.x >> 17;
            float a = ain[src * NH + h] + aoutL[dl * NH + h];
            a = (a > 0.0f) ? a : 0.2f * a;
            att = __expf(a) * __int_as_float(e.y);
            atomicAdd(&ssumL[dl * NH + h], att);
            if (h == 0) {
                atomicAdd(&cntL[dl], 1);
                srcbuf[wv][s] = src;
                dlbuf[wv][s] = dl;
            }
        }
        attbuf[wv][lane] = att;
        // per-wave buffers: same-wave program order + lgkmcnt, no barrier needed
        int nn = min(end - wb, 8);
        for (int ss = 0; ss < nn; ++ss) {
            float att_s = attbuf[wv][(lane & 56) | ss];
            int src_s = srcbuf[wv][ss];
            int dl_s = dlbuf[wv][ss];
            unsigned int vv = hb[(size_t)src_s * 64 + lane];
            atomicAdd(&accE[dl_s * 64 + lane], att_s * __uint_as_float(vv << 16));
            atomicAdd(&accO[dl_s * 64 + lane], att_s * __uint_as_float(vv & 0xffff0000u));
        }
    }
    __syncthreads();

    for (int r = wv; r < NPB; r += 4) {
        int node = node0 + r;
        if (node >= N) break;
        float cc = (float)cntL[r];
        float sm = ssumL[r * NH + h];
        float scale = 1.0f / ((sm / cc + 1e-10f) * cc);
        float o0 = accE[r * 64 + lane] * scale;
        float o1 = accO[r * 64 + lane] * scale;
        *(float2*)(out + (size_t)node * OD + 2 * lane) =
            make_float2(o0 > 0.0f ? o0 : 0.0f, o1 > 0.0f ? o1 : 0.0f);
    }
}

extern "C" void kernel_launch(void* const* d_in, const int* in_sizes, int n_in,
                              void* d_out, int out_size, void* d_ws, size_t ws_size,
                              hipStream_t stream) {
    const float* x     = (const float*)d_in[0];
    const int2*  el    = (const int2*)d_in[1];
    const float* ew    = (const float*)d_in[2];
    const float* W     = (const float*)d_in[3];
    const float* b     = (const float*)d_in[4];
    const float* query = (const float*)d_in[5];
    float* out = (float*)d_out;

    int N = in_sizes[0] / OD;
    int E = in_sizes[1] / 2;
    int total = E + N;
    int NB = (N + NPB - 1) / NPB;            // bins
    int CH = (total + NCH - 1) / NCH;        // edges per chunk
    int n2 = NB * NCH;                        // count-matrix size

    char* ws = (char*)d_ws;
    size_t off = 0;
    auto take = [&](size_t bytes) -> void* {
        void* p = ws + off;
        off = (off + bytes + 255) & ~(size_t)255;
        return p;
    };
    unsigned int* hb = (unsigned int*)take((size_t)N * 64 * 4);  // bf16x2 hidden
    float* ain     = (float*)take((size_t)N * NH * 4);
    float* aout    = (float*)take((size_t)N * NH * 4);
    int*   cnt     = (int*)take((size_t)n2 * 4);
    int*   S       = (int*)take((size_t)(n2 + 1) * 4);
    int*   bsums   = (int*)take(4096);
    int2*  binned  = (int2*)take((size_t)total * 8);
    int2*  sedge   = (int2*)take((size_t)total * 8);

    binhist_kernel<<<NCH, 256, 0, stream>>>(el, cnt, E, total, CH, NB);
    int nb = (n2 + 1023) / 1024;
    scan1_kernel<<<nb, 1024, 0, stream>>>(cnt, S, bsums, n2);
    scan2_kernel<<<1, 1024, 0, stream>>>(bsums, nb);
    scan3b_kernel<<<nb, 1024, 0, stream>>>(S, bsums, cnt, n2);
    binscatter_kernel<<<NCH, 256, 0, stream>>>(el, ew, S, binned, E, total, CH, NB);
    binsort_kernel<<<NB, 256, 0, stream>>>(binned, S, sedge, NB, total);
    gemm_proj_kernel<<<(N + 63) / 64, 256, 0, stream>>>(
        x, W, b, query, (unsigned short*)hb, ain, aout, N);
    aggregate_kernel<<<NB, 256, 0, stream>>>(
        S, sedge, ain, aout, hb, out, N, NB);
}

// Round 8
// 317.688 us; speedup vs baseline: 4.5718x; 4.5718x over previous
//
#include <hip/hip_runtime.h>

#define NH 8
#define DH 16
#define OD 128
#define NCH 256     // scatter chunks (blocks)
#define NPB 128     // nodes per bin
#define ECAP 3072   // max edges per bin held in LDS (mean ~2176, +19 sigma)

typedef __attribute__((ext_vector_type(8))) short bf16x8;
typedef __attribute__((ext_vector_type(4))) float f32x4;

__device__ inline unsigned int f2bf(float f) {
    unsigned int u = __float_as_uint(f);
    return (u + 0x7fffu + ((u >> 16) & 1u)) >> 16;
}

// ---- binned counting sort ----------------------------------------------

// count matrix cnt[bin * NCH + chunk]
__global__ __launch_bounds__(256) void binhist_kernel(const int2* __restrict__ el,
                                                      int* __restrict__ cnt,
                                                      int E, int total, int CH, int NB) {
    __shared__ int lh[1024];
    int t = threadIdx.x, c = blockIdx.x;
    for (int i = t; i < NB; i += 256) lh[i] = 0;
    __syncthreads();
    int beg = c * CH, end = min(total, beg + CH);
    for (int i = beg + t; i < end; i += 256) {
        int dst = (i < E) ? el[i].y : (i - E);
        atomicAdd(&lh[dst >> 7], 1);
    }
    __syncthreads();
    for (int i = t; i < NB; i += 256) cnt[i * NCH + c] = lh[i];
}

__global__ __launch_bounds__(1024) void scan1_kernel(const int* __restrict__ counts,
                                                     int* __restrict__ offsets,
                                                     int* __restrict__ bsums, int n) {
    __shared__ int tmp[1024];
    int t = threadIdx.x;
    int gid = blockIdx.x * 1024 + t;
    int v = (gid < n) ? counts[gid] : 0;
    tmp[t] = v;
    __syncthreads();
    int val = v;
    for (int off = 1; off < 1024; off <<= 1) {
        int add = (t >= off) ? tmp[t - off] : 0;
        __syncthreads();
        val += add;
        tmp[t] = val;
        __syncthreads();
    }
    if (gid < n) offsets[gid] = val - v;
    if (t == 1023) bsums[blockIdx.x] = val;
}

__global__ __launch_bounds__(1024) void scan2_kernel(int* __restrict__ bsums, int nb) {
    __shared__ int tmp[1024];
    int t = threadIdx.x;
    int v = (t < nb) ? bsums[t] : 0;
    tmp[t] = v;
    __syncthreads();
    int val = v;
    for (int off = 1; off < 1024; off <<= 1) {
        int add = (t >= off) ? tmp[t - off] : 0;
        __syncthreads();
        val += add;
        tmp[t] = val;
        __syncthreads();
    }
    if (t < nb) bsums[t] = val - v;
}

__global__ __launch_bounds__(1024) void scan3b_kernel(int* __restrict__ S,
                                                      const int* __restrict__ bsums,
                                                      const int* __restrict__ cnt, int n) {
    int gid = blockIdx.x * 1024 + threadIdx.x;
    if (gid < n) {
        int o = S[gid] + bsums[gid >> 10];
        S[gid] = o;
        if (gid == n - 1) S[n] = o + cnt[gid];
    }
}

// scatter edges into bin-contiguous, chunk-sequential regions.
// payload: word0 = src | (dstLocal << 17), word1 = edge weight bits
__global__ __launch_bounds__(256) void binscatter_kernel(const int2* __restrict__ el,
                                                         const float* __restrict__ ew,
                                                         const int* __restrict__ S,
                                                         int2* __restrict__ binned,
                                                         int E, int total, int CH, int NB) {
    __shared__ int lcur[1024];
    int t = threadIdx.x, c = blockIdx.x;
    for (int i = t; i < NB; i += 256) lcur[i] = S[i * NCH + c];
    __syncthreads();
    int beg = c * CH, end = min(total, beg + CH);
    for (int i = beg + t; i < end; i += 256) {
        int src, dst; float w;
        if (i < E) { int2 e = el[i]; src = e.x; dst = e.y; w = ew[i]; }
        else       { src = dst = i - E; w = 1.0f; }
        int b = dst >> 7;
        int pos = atomicAdd(&lcur[b], 1);
        binned[pos] = make_int2(src | ((dst & 127) << 17), __float_as_int(w));
    }
}

// one block per bin: LDS counting sort by dstLocal, emit sorted sedge + offsets
__global__ __launch_bounds__(256) void binsort_kernel(const int2* __restrict__ binned,
                                                      const int* __restrict__ S,
                                                      int2* __restrict__ sedge,
                                                      int* __restrict__ offsets,
                                                      int N, int NB, int total) {
    __shared__ int2 eb[ECAP];
    __shared__ int lh[NPB];
    __shared__ int cu[NPB];
    int b = blockIdx.x, t = threadIdx.x;
    int base = S[b * NCH];
    int endb = S[(b + 1) * NCH];
    int cnt = min(endb - base, ECAP);

    for (int i = t; i < NPB; i += 256) lh[i] = 0;
    __syncthreads();
    for (int i = t; i < cnt; i += 256) {
        int2 e = binned[base + i];
        eb[i] = e;
        atomicAdd(&lh[(e.x >> 17) & 127], 1);
    }
    __syncthreads();
    // exclusive scan of lh[0..NPB) by wave 0 (2 counters per lane)
    if (t < 64) {
        int loc[2]; int s = 0;
#pragma unroll
        for (int j = 0; j < 2; ++j) { loc[j] = lh[t * 2 + j]; s += loc[j]; }
        int inc = s;
        for (int d = 1; d < 64; d <<= 1) {
            int o = __shfl_up(inc, d, 64);
            if (t >= d) inc += o;
        }
        int ex = inc - s;
#pragma unroll
        for (int j = 0; j < 2; ++j) { cu[t * 2 + j] = ex; ex += loc[j]; }
    }
    __syncthreads();
    int node0 = b << 7;
    for (int i = t; i < NPB; i += 256) {
        int node = node0 + i;
        if (node < N) offsets[node] = base + cu[i];
    }
    if (b == NB - 1 && t == 0) offsets[N] = total;
    __syncthreads();
    for (int i = t; i < cnt; i += 256) {
        int2 e = eb[i];
        int d = (e.x >> 17) & 127;
        int pos = atomicAdd(&cu[d], 1);
        sedge[base + pos] = e;   // keep dl in payload
    }
}

// ---- MFMA bf16 GEMM: hidden = x@W + b ----------------------------------
__global__ __launch_bounds__(256) void gemm_proj_kernel(
        const float* __restrict__ x, const float* __restrict__ W,
        const float* __restrict__ b, const float* __restrict__ query,
        unsigned short* __restrict__ hbu, float* __restrict__ ain,
        float* __restrict__ aout, int N) {
    __shared__ unsigned short xs[64 * 136];
    __shared__ unsigned short wt[128 * 136];
    int t = threadIdx.x;
    int row0 = blockIdx.x * 64;

    {
        const float4* x4 = (const float4*)x;
#pragma unroll
        for (int i = 0; i < 8; ++i) {
            int f = t + i * 256;
            int row = f >> 5, c4 = f & 31;
            int gr = row0 + row;
            if (gr >= N) gr = N - 1;
            float4 v = x4[(size_t)gr * 32 + c4];
            unsigned int u0 = f2bf(v.x) | (f2bf(v.y) << 16);
            unsigned int u1 = f2bf(v.z) | (f2bf(v.w) << 16);
            *(uint2*)&xs[row * 136 + 4 * c4] = make_uint2(u0, u1);
        }
    }
    {
        const float4* W4 = (const float4*)W;
#pragma unroll
        for (int i = 0; i < 16; ++i) {
            int f = t + i * 256;
            int k = f & 127, c4 = f >> 7;
            float4 v = W4[k * 32 + c4];
            wt[(4 * c4 + 0) * 136 + k] = (unsigned short)f2bf(v.x);
            wt[(4 * c4 + 1) * 136 + k] = (unsigned short)f2bf(v.y);
            wt[(4 * c4 + 2) * 136 + k] = (unsigned short)f2bf(v.z);
            wt[(4 * c4 + 3) * 136 + k] = (unsigned short)f2bf(v.w);
        }
    }
    __syncthreads();

    int lane = t & 63, wv = t >> 6;
    int d = lane & 15, g = lane >> 4;
    int tbase = wv * 16;

    bf16x8 af[4];
#pragma unroll
    for (int s = 0; s < 4; ++s)
        af[s] = *(bf16x8*)&xs[(tbase + d) * 136 + s * 32 + g * 8];

    f32x4 acc[8];
#pragma unroll
    for (int c = 0; c < 8; ++c) acc[c] = (f32x4){0.f, 0.f, 0.f, 0.f};

#pragma unroll
    for (int c = 0; c < 8; ++c) {
#pragma unroll
        for (int s = 0; s < 4; ++s) {
            bf16x8 bf = *(bf16x8*)&wt[(d + 16 * c) * 136 + s * 32 + g * 8];
            acc[c] = __builtin_amdgcn_mfma_f32_16x16x32_bf16(af[s], bf, acc[c], 0, 0, 0);
        }
    }

    int rbase = row0 + tbase + g * 4;
#pragma unroll
    for (int c = 0; c < 8; ++c) {
        float bc = b[d + 16 * c];
        float2 q2 = *(const float2*)(query + c * 2 * DH + 2 * d);
#pragma unroll
        for (int j = 0; j < 4; ++j) {
            float v = acc[c][j] + bc;
            int row = rbase + j;
            if (row < N) hbu[(size_t)row * OD + d + 16 * c] = (unsigned short)f2bf(v);
            float pin = q2.x * v, pout = q2.y * v;
#pragma unroll
            for (int m = 1; m < 16; m <<= 1) {
                pin  += __shfl_xor(pin, m, 64);
                pout += __shfl_xor(pout, m, 64);
            }
            if (d == 0 && row < N) {
                ain[row * NH + c] = pin;
                aout[row * NH + c] = pout;
            }
        }
    }
}

// ---- edge attention: att[h][idx] (bf16), srcArr[idx], scale[n][h] -------
// one block per bin; thread t: head h = t>>5, edge slot ii = t&31.
__global__ __launch_bounds__(256) void edgeatt_kernel(
        const int* __restrict__ S, const int2* __restrict__ sedge,
        const int* __restrict__ offsets, const float* __restrict__ ain,
        const float* __restrict__ aout, unsigned short* __restrict__ attB,
        int* __restrict__ srcArr, float* __restrict__ scaleG,
        int N, int totalE) {
    __shared__ float aoutL[NPB * NH];   // 4 KB
    __shared__ float normL[NPB * NH];   // 4 KB
    int b = blockIdx.x, t = threadIdx.x;
    int base = S[b * NCH], end = S[(b + 1) * NCH];
    int node0 = b * NPB;

    for (int i = t; i < NPB * NH; i += 256) normL[i] = 0.0f;
    // preload aout rows for this bin: 1024 floats = 256 float4
    ((float4*)aoutL)[t] = ((const float4*)aout)[(size_t)node0 * 2 + t];
    __syncthreads();

    int h = t >> 5, ii = t & 31;
    size_t hbase = (size_t)h * totalE;
    for (int i0 = base; i0 < end; i0 += 32) {
        int idx = i0 + ii;
        if (idx < end) {
            int2 e = sedge[idx];
            int src = e.x & 0x1FFFF, dl = (e.x >> 17) & 127;
            float a = ain[src * NH + h] + aoutL[dl * NH + h];
            a = (a > 0.0f) ? a : 0.2f * a;
            float att = __expf(a) * __int_as_float(e.y);
            attB[hbase + idx] = (unsigned short)f2bf(att);
            atomicAdd(&normL[dl * NH + h], att);
            if (h == 0) srcArr[idx] = src;
        }
    }
    __syncthreads();
    for (int j = t; j < NPB * NH; j += 256) {
        int node = node0 + (j >> 3);
        if (node < N) {
            float c = (float)(offsets[node + 1] - offsets[node]);
            float sm = normL[j];
            scaleG[node * NH + (j & 7)] = 1.0f / ((sm / c + 1e-10f) * c);
        }
    }
}

// ---- aggregate: one wave per node, half-wave per edge -------------------
// lane = (half = l>>5, q = l&31). lane owns dims 4q..4q+3 of its half's edge.
// head h = q>>2. Final: acc += shfl_xor(acc,32); half 0 writes float4.
__global__ __launch_bounds__(256) void aggregate_kernel(
        const int* __restrict__ offsets, const int* __restrict__ srcArr,
        const unsigned short* __restrict__ attB, const float* __restrict__ scaleG,
        const uint2* __restrict__ hb2, float* __restrict__ out,
        int N, int totalE) {
    int n = (blockIdx.x * blockDim.x + threadIdx.x) >> 6;
    int lane = threadIdx.x & 63;
    if (n >= N) return;
    int beg = offsets[n], end = offsets[n + 1];
    int half = lane >> 5, q = lane & 31;
    int h = q >> 2;
    const unsigned short* attRow = attB + (size_t)h * totalE;

    float4 acc = make_float4(0.f, 0.f, 0.f, 0.f);
    for (int i = beg; i < end; i += 4) {
        int ib = i + 2 * half;          // this lane's 2 edges: ib, ib+1
        int s0 = srcArr[ib] & 0x1FFFF;          // padded reads past end are safe
        int s1 = srcArr[ib + 1] & 0x1FFFF;
        float a0 = (ib < end)     ? __uint_as_float((unsigned int)attRow[ib] << 16)     : 0.0f;
        float a1 = (ib + 1 < end) ? __uint_as_float((unsigned int)attRow[ib + 1] << 16) : 0.0f;
        uint2 w0 = hb2[(size_t)s0 * 32 + q];
        uint2 w1 = hb2[(size_t)s1 * 32 + q];
        acc.x += a0 * __uint_as_float(w0.x << 16);
        acc.y += a0 * __uint_as_float(w0.x & 0xffff0000u);
        acc.z += a0 * __uint_as_float(w0.y << 16);
        acc.w += a0 * __uint_as_float(w0.y & 0xffff0000u);
        acc.x += a1 * __uint_as_float(w1.x << 16);
        acc.y += a1 * __uint_as_float(w1.x & 0xffff0000u);
        acc.z += a1 * __uint_as_float(w1.y << 16);
        acc.w += a1 * __uint_as_float(w1.y & 0xffff0000u);
    }
    acc.x += __shfl_xor(acc.x, 32, 64);
    acc.y += __shfl_xor(acc.y, 32, 64);
    acc.z += __shfl_xor(acc.z, 32, 64);
    acc.w += __shfl_xor(acc.w, 32, 64);
    if (half == 0) {
        float sc = scaleG[n * NH + h];
        float4 o;
        o.x = acc.x * sc; o.y = acc.y * sc; o.z = acc.z * sc; o.w = acc.w * sc;
        o.x = o.x > 0.f ? o.x : 0.f;
        o.y = o.y > 0.f ? o.y : 0.f;
        o.z = o.z > 0.f ? o.z : 0.f;
        o.w = o.w > 0.f ? o.w : 0.f;
        *(float4*)(out + (size_t)n * OD + 4 * q) = o;
    }
}

extern "C" void kernel_launch(void* const* d_in, const int* in_sizes, int n_in,
                              void* d_out, int out_size, void* d_ws, size_t ws_size,
                              hipStream_t stream) {
    const float* x     = (const float*)d_in[0];
    const int2*  el    = (const int2*)d_in[1];
    const float* ew    = (const float*)d_in[2];
    const float* W     = (const float*)d_in[3];
    const float* b     = (const float*)d_in[4];
    const float* query = (const float*)d_in[5];
    float* out = (float*)d_out;

    int N = in_sizes[0] / OD;
    int E = in_sizes[1] / 2;
    int total = E + N;
    int NB = (N + NPB - 1) / NPB;            // bins
    int CH = (total + NCH - 1) / NCH;        // edges per chunk
    int n2 = NB * NCH;                        // count-matrix size

    char* ws = (char*)d_ws;
    size_t off = 0;
    auto take = [&](size_t bytes) -> void* {
        void* p = ws + off;
        off = (off + bytes + 255) & ~(size_t)255;
        return p;
    };
    unsigned int* hb = (unsigned int*)take((size_t)N * 64 * 4);  // bf16x2 hidden
    float* ain     = (float*)take((size_t)N * NH * 4);
    float* aout    = (float*)take((size_t)(N + NPB) * NH * 4);   // pad for bin preload
    int*   cnt     = (int*)take((size_t)n2 * 4);
    int*   S       = (int*)take((size_t)(n2 + 1) * 4);
    int*   offsets = (int*)take((size_t)(N + 1) * 4);
    int*   bsums   = (int*)take(4096);
    int2*  binned  = (int2*)take((size_t)total * 8);
    int2*  sedge   = (int2*)take((size_t)total * 8);
    unsigned short* attB = (unsigned short*)take(((size_t)total * NH + 16) * 2);
    // srcArr + scaleG alias the (dead-after-binsort) binned buffer
    int*   srcArr  = (int*)binned;
    float* scaleG  = (float*)((char*)binned + ((size_t)total + 16) * 4);

    binhist_kernel<<<NCH, 256, 0, stream>>>(el, cnt, E, total, CH, NB);
    int nb = (n2 + 1023) / 1024;
    scan1_kernel<<<nb, 1024, 0, stream>>>(cnt, S, bsums, n2);
    scan2_kernel<<<1, 1024, 0, stream>>>(bsums, nb);
    scan3b_kernel<<<nb, 1024, 0, stream>>>(S, bsums, cnt, n2);
    binscatter_kernel<<<NCH, 256, 0, stream>>>(el, ew, S, binned, E, total, CH, NB);
    binsort_kernel<<<NB, 256, 0, stream>>>(binned, S, sedge, offsets, N, NB, total);
    gemm_proj_kernel<<<(N + 63) / 64, 256, 0, stream>>>(
        x, W, b, query, (unsigned short*)hb, ain, aout, N);
    edgeatt_kernel<<<NB, 256, 0, stream>>>(
        S, sedge, offsets, ain, aout, attB, srcArr, scaleG, N, total);
    aggregate_kernel<<<((size_t)N * 64 + 255) / 256, 256, 0, stream>>>(
        offsets, srcArr, attB, scaleG, (const uint2*)hb, out, N, total);
}

// Round 9
// 313.064 us; speedup vs baseline: 4.6393x; 1.0148x over previous
//
#include <hip/hip_runtime.h>

#define NH 8
#define DH 16
#define OD 128
#define NCH 256     // scatter chunks (blocks)
#define NPB 128     // nodes per bin
#define ECAP 3072   // max edges per bin held in LDS (mean ~2176, +19 sigma)

typedef __attribute__((ext_vector_type(8))) short bf16x8;
typedef __attribute__((ext_vector_type(4))) float f32x4;

__device__ inline unsigned int f2bf(float f) {
    unsigned int u = __float_as_uint(f);
    return (u + 0x7fffu + ((u >> 16) & 1u)) >> 16;
}

// ---- binned counting sort ----------------------------------------------

// count matrix cnt[bin * NCH + chunk]
__global__ __launch_bounds__(256) void binhist_kernel(const int2* __restrict__ el,
                                                      int* __restrict__ cnt,
                                                      int E, int total, int CH, int NB) {
    __shared__ int lh[1024];
    int t = threadIdx.x, c = blockIdx.x;
    for (int i = t; i < NB; i += 256) lh[i] = 0;
    __syncthreads();
    int beg = c * CH, end = min(total, beg + CH);
    for (int i = beg + t; i < end; i += 256) {
        int dst = (i < E) ? el[i].y : (i - E);
        atomicAdd(&lh[dst >> 7], 1);
    }
    __syncthreads();
    for (int i = t; i < NB; i += 256) cnt[i * NCH + c] = lh[i];
}

__global__ __launch_bounds__(1024) void scan1_kernel(const int* __restrict__ counts,
                                                     int* __restrict__ offsets,
                                                     int* __restrict__ bsums, int n) {
    __shared__ int tmp[1024];
    int t = threadIdx.x;
    int gid = blockIdx.x * 1024 + t;
    int v = (gid < n) ? counts[gid] : 0;
    tmp[t] = v;
    __syncthreads();
    int val = v;
    for (int off = 1; off < 1024; off <<= 1) {
        int add = (t >= off) ? tmp[t - off] : 0;
        __syncthreads();
        val += add;
        tmp[t] = val;
        __syncthreads();
    }
    if (gid < n) offsets[gid] = val - v;
    if (t == 1023) bsums[blockIdx.x] = val;
}

__global__ __launch_bounds__(1024) void scan2_kernel(int* __restrict__ bsums, int nb) {
    __shared__ int tmp[1024];
    int t = threadIdx.x;
    int v = (t < nb) ? bsums[t] : 0;
    tmp[t] = v;
    __syncthreads();
    int val = v;
    for (int off = 1; off < 1024; off <<= 1) {
        int add = (t >= off) ? tmp[t - off] : 0;
        __syncthreads();
        val += add;
        tmp[t] = val;
        __syncthreads();
    }
    if (t < nb) bsums[t] = val - v;
}

__global__ __launch_bounds__(1024) void scan3b_kernel(int* __restrict__ S,
                                                      const int* __restrict__ bsums,
                                                      const int* __restrict__ cnt, int n) {
    int gid = blockIdx.x * 1024 + threadIdx.x;
    if (gid < n) {
        int o = S[gid] + bsums[gid >> 10];
        S[gid] = o;
        if (gid == n - 1) S[n] = o + cnt[gid];
    }
}

// scatter edges into bin-contiguous, chunk-sequential regions.
// payload: word0 = src | (dstLocal << 17), word1 = edge weight bits
__global__ __launch_bounds__(256) void binscatter_kernel(const int2* __restrict__ el,
                                                         const float* __restrict__ ew,
                                                         const int* __restrict__ S,
                                                         int2* __restrict__ binned,
                                                         int E, int total, int CH, int NB) {
    __shared__ int lcur[1024];
    int t = threadIdx.x, c = blockIdx.x;
    for (int i = t; i < NB; i += 256) lcur[i] = S[i * NCH + c];
    __syncthreads();
    int beg = c * CH, end = min(total, beg + CH);
    for (int i = beg + t; i < end; i += 256) {
        int src, dst; float w;
        if (i < E) { int2 e = el[i]; src = e.x; dst = e.y; w = ew[i]; }
        else       { src = dst = i - E; w = 1.0f; }
        int b = dst >> 7;
        int pos = atomicAdd(&lcur[b], 1);
        binned[pos] = make_int2(src | ((dst & 127) << 17), __float_as_int(w));
    }
}

// one block per bin: LDS counting sort by dstLocal, emit sorted sedge + offsets
__global__ __launch_bounds__(256) void binsort_kernel(const int2* __restrict__ binned,
                                                      const int* __restrict__ S,
                                                      int2* __restrict__ sedge,
                                                      int* __restrict__ offsets,
                                                      int N, int NB, int total) {
    __shared__ int2 eb[ECAP];
    __shared__ int lh[NPB];
    __shared__ int cu[NPB];
    int b = blockIdx.x, t = threadIdx.x;
    int base = S[b * NCH];
    int endb = S[(b + 1) * NCH];
    int cnt = min(endb - base, ECAP);

    for (int i = t; i < NPB; i += 256) lh[i] = 0;
    __syncthreads();
    for (int i = t; i < cnt; i += 256) {
        int2 e = binned[base + i];
        eb[i] = e;
        atomicAdd(&lh[(e.x >> 17) & 127], 1);
    }
    __syncthreads();
    // exclusive scan of lh[0..NPB) by wave 0 (2 counters per lane)
    if (t < 64) {
        int loc[2]; int s = 0;
#pragma unroll
        for (int j = 0; j < 2; ++j) { loc[j] = lh[t * 2 + j]; s += loc[j]; }
        int inc = s;
        for (int d = 1; d < 64; d <<= 1) {
            int o = __shfl_up(inc, d, 64);
            if (t >= d) inc += o;
        }
        int ex = inc - s;
#pragma unroll
        for (int j = 0; j < 2; ++j) { cu[t * 2 + j] = ex; ex += loc[j]; }
    }
    __syncthreads();
    int node0 = b << 7;
    for (int i = t; i < NPB; i += 256) {
        int node = node0 + i;
        if (node < N) offsets[node] = base + cu[i];
    }
    if (b == NB - 1 && t == 0) offsets[N] = total;
    __syncthreads();
    for (int i = t; i < cnt; i += 256) {
        int2 e = eb[i];
        int d = (e.x >> 17) & 127;
        int pos = atomicAdd(&cu[d], 1);
        sedge[base + pos] = e;   // keep dl in payload
    }
}

// ---- MFMA bf16 GEMM: hidden = x@W + b ----------------------------------
__global__ __launch_bounds__(256) void gemm_proj_kernel(
        const float* __restrict__ x, const float* __restrict__ W,
        const float* __restrict__ b, const float* __restrict__ query,
        unsigned short* __restrict__ hbu, float* __restrict__ ain,
        float* __restrict__ aout, int N) {
    __shared__ unsigned short xs[64 * 136];
    __shared__ unsigned short wt[128 * 136];
    int t = threadIdx.x;
    int row0 = blockIdx.x * 64;

    {
        const float4* x4 = (const float4*)x;
#pragma unroll
        for (int i = 0; i < 8; ++i) {
            int f = t + i * 256;
            int row = f >> 5, c4 = f & 31;
            int gr = row0 + row;
            if (gr >= N) gr = N - 1;
            float4 v = x4[(size_t)gr * 32 + c4];
            unsigned int u0 = f2bf(v.x) | (f2bf(v.y) << 16);
            unsigned int u1 = f2bf(v.z) | (f2bf(v.w) << 16);
            *(uint2*)&xs[row * 136 + 4 * c4] = make_uint2(u0, u1);
        }
    }
    {
        const float4* W4 = (const float4*)W;
#pragma unroll
        for (int i = 0; i < 16; ++i) {
            int f = t + i * 256;
            int k = f & 127, c4 = f >> 7;
            float4 v = W4[k * 32 + c4];
            wt[(4 * c4 + 0) * 136 + k] = (unsigned short)f2bf(v.x);
            wt[(4 * c4 + 1) * 136 + k] = (unsigned short)f2bf(v.y);
            wt[(4 * c4 + 2) * 136 + k] = (unsigned short)f2bf(v.z);
            wt[(4 * c4 + 3) * 136 + k] = (unsigned short)f2bf(v.w);
        }
    }
    __syncthreads();

    int lane = t & 63, wv = t >> 6;
    int d = lane & 15, g = lane >> 4;
    int tbase = wv * 16;

    bf16x8 af[4];
#pragma unroll
    for (int s = 0; s < 4; ++s)
        af[s] = *(bf16x8*)&xs[(tbase + d) * 136 + s * 32 + g * 8];

    f32x4 acc[8];
#pragma unroll
    for (int c = 0; c < 8; ++c) acc[c] = (f32x4){0.f, 0.f, 0.f, 0.f};

#pragma unroll
    for (int c = 0; c < 8; ++c) {
#pragma unroll
        for (int s = 0; s < 4; ++s) {
            bf16x8 bf = *(bf16x8*)&wt[(d + 16 * c) * 136 + s * 32 + g * 8];
            acc[c] = __builtin_amdgcn_mfma_f32_16x16x32_bf16(af[s], bf, acc[c], 0, 0, 0);
        }
    }

    int rbase = row0 + tbase + g * 4;
#pragma unroll
    for (int c = 0; c < 8; ++c) {
        float bc = b[d + 16 * c];
        float2 q2 = *(const float2*)(query + c * 2 * DH + 2 * d);
#pragma unroll
        for (int j = 0; j < 4; ++j) {
            float v = acc[c][j] + bc;
            int row = rbase + j;
            if (row < N) hbu[(size_t)row * OD + d + 16 * c] = (unsigned short)f2bf(v);
            float pin = q2.x * v, pout = q2.y * v;
#pragma unroll
            for (int m = 1; m < 16; m <<= 1) {
                pin  += __shfl_xor(pin, m, 64);
                pout += __shfl_xor(pout, m, 64);
            }
            if (d == 0 && row < N) {
                ain[row * NH + c] = pin;
                aout[row * NH + c] = pout;
            }
        }
    }
}

// ---- edge attention: att[h][idx] (bf16), srcArr[idx], scale[n][h] -------
// one block per bin; thread t: head h = t>>5, edge slot ii = t&31.
// 4-edge batched loads for MLP.
__global__ __launch_bounds__(256) void edgeatt_kernel(
        const int* __restrict__ S, const int2* __restrict__ sedge,
        const int* __restrict__ offsets, const float* __restrict__ ain,
        const float* __restrict__ aout, unsigned short* __restrict__ attB,
        int* __restrict__ srcArr, float* __restrict__ scaleG,
        int N, int totalE) {
    __shared__ float aoutL[NPB * NH];   // 4 KB
    __shared__ float normL[NPB * NH];   // 4 KB
    int b = blockIdx.x, t = threadIdx.x;
    int base = S[b * NCH], end = S[(b + 1) * NCH];
    int node0 = b * NPB;

    for (int i = t; i < NPB * NH; i += 256) normL[i] = 0.0f;
    // preload aout rows for this bin: 1024 floats = 256 float4
    ((float4*)aoutL)[t] = ((const float4*)aout)[(size_t)node0 * 2 + t];
    __syncthreads();

    int h = t >> 5, ii = t & 31;
    size_t hbase = (size_t)h * totalE;
    for (int i0 = base; i0 < end; i0 += 128) {
        int idx[4]; int2 e[4];
#pragma unroll
        for (int k = 0; k < 4; ++k) {
            idx[k] = i0 + ii + 32 * k;
            e[k] = (idx[k] < end) ? sedge[idx[k]] : make_int2(0, 0);
        }
        float av[4];
#pragma unroll
        for (int k = 0; k < 4; ++k)
            av[k] = ain[(e[k].x & 0x1FFFF) * NH + h];
#pragma unroll
        for (int k = 0; k < 4; ++k) {
            if (idx[k] < end) {
                int src = e[k].x & 0x1FFFF, dl = (e[k].x >> 17) & 127;
                float a = av[k] + aoutL[dl * NH + h];
                a = (a > 0.0f) ? a : 0.2f * a;
                float att = __expf(a) * __int_as_float(e[k].y);
                attB[hbase + idx[k]] = (unsigned short)f2bf(att);
                atomicAdd(&normL[dl * NH + h], att);
                if (h == 0) srcArr[idx[k]] = src;
            }
        }
    }
    __syncthreads();
    for (int j = t; j < NPB * NH; j += 256) {
        int node = node0 + (j >> 3);
        if (node < N) {
            float c = (float)(offsets[node + 1] - offsets[node]);
            float sm = normL[j];
            scaleG[node * NH + (j & 7)] = 1.0f / ((sm / c + 1e-10f) * c);
        }
    }
}

// ---- aggregate: one wave per node, half-wave per edge group -------------
// lane = (half = l>>5, q = l&31). lane owns dims 4q..4q+3. head h = q>>2.
// 4 edges per half per iteration (8 per wave) for MLP.
__global__ __launch_bounds__(256) void aggregate_kernel(
        const int* __restrict__ offsets, const int* __restrict__ srcArr,
        const unsigned short* __restrict__ attB, const float* __restrict__ scaleG,
        const uint2* __restrict__ hb2, float* __restrict__ out,
        int N, int totalE) {
    int n = (blockIdx.x * blockDim.x + threadIdx.x) >> 6;
    int lane = threadIdx.x & 63;
    if (n >= N) return;
    int beg = offsets[n], end = offsets[n + 1];
    int half = lane >> 5, q = lane & 31;
    int h = q >> 2;
    const unsigned short* attRow = attB + (size_t)h * totalE;

    float4 acc = make_float4(0.f, 0.f, 0.f, 0.f);
    for (int i = beg; i < end; i += 8) {
        int ib = i + 4 * half;          // this lane's 4 edges: ib..ib+3
        int s[4]; float a[4];
#pragma unroll
        for (int k = 0; k < 4; ++k) {
            s[k] = srcArr[ib + k] & 0x1FFFF;   // padded reads past end are mapped
            a[k] = (ib + k < end)
                 ? __uint_as_float((unsigned int)attRow[ib + k] << 16) : 0.0f;
        }
        uint2 w[4];
#pragma unroll
        for (int k = 0; k < 4; ++k)
            w[k] = hb2[(size_t)s[k] * 32 + q];
#pragma unroll
        for (int k = 0; k < 4; ++k) {
            acc.x += a[k] * __uint_as_float(w[k].x << 16);
            acc.y += a[k] * __uint_as_float(w[k].x & 0xffff0000u);
            acc.z += a[k] * __uint_as_float(w[k].y << 16);
            acc.w += a[k] * __uint_as_float(w[k].y & 0xffff0000u);
        }
    }
    acc.x += __shfl_xor(acc.x, 32, 64);
    acc.y += __shfl_xor(acc.y, 32, 64);
    acc.z += __shfl_xor(acc.z, 32, 64);
    acc.w += __shfl_xor(acc.w, 32, 64);
    if (half == 0) {
        float sc = scaleG[n * NH + h];
        float4 o;
        o.x = acc.x * sc; o.y = acc.y * sc; o.z = acc.z * sc; o.w = acc.w * sc;
        o.x = o.x > 0.f ? o.x : 0.f;
        o.y = o.y > 0.f ? o.y : 0.f;
        o.z = o.z > 0.f ? o.z : 0.f;
        o.w = o.w > 0.f ? o.w : 0.f;
        *(float4*)(out + (size_t)n * OD + 4 * q) = o;
    }
}

extern "C" void kernel_launch(void* const* d_in, const int* in_sizes, int n_in,
                              void* d_out, int out_size, void* d_ws, size_t ws_size,
                              hipStream_t stream) {
    const float* x     = (const float*)d_in[0];
    const int2*  el    = (const int2*)d_in[1];
    const float* ew    = (const float*)d_in[2];
    const float* W     = (const float*)d_in[3];
    const float* b     = (const float*)d_in[4];
    const float* query = (const float*)d_in[5];
    float* out = (float*)d_out;

    int N = in_sizes[0] / OD;
    int E = in_sizes[1] / 2;
    int total = E + N;
    int NB = (N + NPB - 1) / NPB;            // bins
    int CH = (total + NCH - 1) / NCH;        // edges per chunk
    int n2 = NB * NCH;                        // count-matrix size

    char* ws = (char*)d_ws;
    size_t off = 0;
    auto take = [&](size_t bytes) -> void* {
        void* p = ws + off;
        off = (off + bytes + 255) & ~(size_t)255;
        return p;
    };
    unsigned int* hb = (unsigned int*)take((size_t)N * 64 * 4);  // bf16x2 hidden
    float* ain     = (float*)take((size_t)N * NH * 4);
    float* aout    = (float*)take((size_t)(N + NPB) * NH * 4);   // pad for bin preload
    int*   cnt     = (int*)take((size_t)n2 * 4);
    int*   S       = (int*)take((size_t)(n2 + 1) * 4);
    int*   offsets = (int*)take((size_t)(N + 1) * 4);
    int*   bsums   = (int*)take(4096);
    int2*  binned  = (int2*)take((size_t)total * 8);
    int2*  sedge   = (int2*)take((size_t)total * 8);
    unsigned short* attB = (unsigned short*)take(((size_t)total * NH + 16) * 2);
    // srcArr + scaleG alias the (dead-after-binsort) binned buffer
    int*   srcArr  = (int*)binned;
    float* scaleG  = (float*)((char*)binned + ((size_t)total + 16) * 4);

    binhist_kernel<<<NCH, 256, 0, stream>>>(el, cnt, E, total, CH, NB);
    int nb = (n2 + 1023) / 1024;
    scan1_kernel<<<nb, 1024, 0, stream>>>(cnt, S, bsums, n2);
    scan2_kernel<<<1, 1024, 0, stream>>>(bsums, nb);
    scan3b_kernel<<<nb, 1024, 0, stream>>>(S, bsums, cnt, n2);
    binscatter_kernel<<<NCH, 256, 0, stream>>>(el, ew, S, binned, E, total, CH, NB);
    binsort_kernel<<<NB, 256, 0, stream>>>(binned, S, sedge, offsets, N, NB, total);
    gemm_proj_kernel<<<(N + 63) / 64, 256, 0, stream>>>(
        x, W, b, query, (unsigned short*)hb, ain, aout, N);
    edgeatt_kernel<<<NB, 256, 0, stream>>>(
        S, sedge, offsets, ain, aout, attB, srcArr, scaleG, N, total);
    aggregate_kernel<<<((size_t)N * 64 + 255) / 256, 256, 0, stream>>>(
        offsets, srcArr, attB, scaleG, (const uint2*)hb, out, N, total);
}

// Round 10
// 235.604 us; speedup vs baseline: 6.1646x; 1.3288x over previous
//
#include <hip/hip_runtime.h>

#define NH 8
#define DH 16
#define OD 128
#define NCH 256     // scatter chunks (blocks)
#define NPB 128     // nodes per bin
#define ECAP 3072   // max edges per bin held in LDS (mean ~2176, +19 sigma)

typedef __attribute__((ext_vector_type(8))) short bf16x8;
typedef __attribute__((ext_vector_type(4))) float f32x4;

__device__ inline unsigned int f2bf(float f) {
    unsigned int u = __float_as_uint(f);
    return (u + 0x7fffu + ((u >> 16) & 1u)) >> 16;
}

// ---- binned counting sort ----------------------------------------------

// count matrix cnt[bin * NCH + chunk]
__global__ __launch_bounds__(256) void binhist_kernel(const int2* __restrict__ el,
                                                      int* __restrict__ cnt,
                                                      int E, int total, int CH, int NB) {
    __shared__ int lh[1024];
    int t = threadIdx.x, c = blockIdx.x;
    for (int i = t; i < NB; i += 256) lh[i] = 0;
    __syncthreads();
    int beg = c * CH, end = min(total, beg + CH);
    for (int i = beg + t; i < end; i += 256) {
        int dst = (i < E) ? el[i].y : (i - E);
        atomicAdd(&lh[dst >> 7], 1);
    }
    __syncthreads();
    for (int i = t; i < NB; i += 256) cnt[i * NCH + c] = lh[i];
}

__global__ __launch_bounds__(1024) void scan1_kernel(const int* __restrict__ counts,
                                                     int* __restrict__ offsets,
                                                     int* __restrict__ bsums, int n) {
    __shared__ int tmp[1024];
    int t = threadIdx.x;
    int gid = blockIdx.x * 1024 + t;
    int v = (gid < n) ? counts[gid] : 0;
    tmp[t] = v;
    __syncthreads();
    int val = v;
    for (int off = 1; off < 1024; off <<= 1) {
        int add = (t >= off) ? tmp[t - off] : 0;
        __syncthreads();
        val += add;
        tmp[t] = val;
        __syncthreads();
    }
    if (gid < n) offsets[gid] = val - v;
    if (t == 1023) bsums[blockIdx.x] = val;
}

__global__ __launch_bounds__(1024) void scan2_kernel(int* __restrict__ bsums, int nb) {
    __shared__ int tmp[1024];
    int t = threadIdx.x;
    int v = (t < nb) ? bsums[t] : 0;
    tmp[t] = v;
    __syncthreads();
    int val = v;
    for (int off = 1; off < 1024; off <<= 1) {
        int add = (t >= off) ? tmp[t - off] : 0;
        __syncthreads();
        val += add;
        tmp[t] = val;
        __syncthreads();
    }
    if (t < nb) bsums[t] = val - v;
}

__global__ __launch_bounds__(1024) void scan3b_kernel(int* __restrict__ S,
                                                      const int* __restrict__ bsums,
                                                      const int* __restrict__ cnt, int n) {
    int gid = blockIdx.x * 1024 + threadIdx.x;
    if (gid < n) {
        int o = S[gid] + bsums[gid >> 10];
        S[gid] = o;
        if (gid == n - 1) S[n] = o + cnt[gid];
    }
}

// scatter edges into bin-contiguous, chunk-sequential regions.
// payload: word0 = src | (dstLocal << 17), word1 = edge weight bits
__global__ __launch_bounds__(256) void binscatter_kernel(const int2* __restrict__ el,
                                                         const float* __restrict__ ew,
                                                         const int* __restrict__ S,
                                                         int2* __restrict__ binned,
                                                         int E, int total, int CH, int NB) {
    __shared__ int lcur[1024];
    int t = threadIdx.x, c = blockIdx.x;
    for (int i = t; i < NB; i += 256) lcur[i] = S[i * NCH + c];
    __syncthreads();
    int beg = c * CH, end = min(total, beg + CH);
    for (int i = beg + t; i < end; i += 256) {
        int src, dst; float w;
        if (i < E) { int2 e = el[i]; src = e.x; dst = e.y; w = ew[i]; }
        else       { src = dst = i - E; w = 1.0f; }
        int b = dst >> 7;
        int pos = atomicAdd(&lcur[b], 1);
        binned[pos] = make_int2(src | ((dst & 127) << 17), __float_as_int(w));
    }
}

// one block per bin: LDS counting sort by dstLocal, emit sorted sedge + offsets
__global__ __launch_bounds__(256) void binsort_kernel(const int2* __restrict__ binned,
                                                      const int* __restrict__ S,
                                                      int2* __restrict__ sedge,
                                                      int* __restrict__ offsets,
                                                      int N, int NB, int total) {
    __shared__ int2 eb[ECAP];
    __shared__ int lh[NPB];
    __shared__ int cu[NPB];
    int b = blockIdx.x, t = threadIdx.x;
    int base = S[b * NCH];
    int endb = S[(b + 1) * NCH];
    int cnt = min(endb - base, ECAP);

    for (int i = t; i < NPB; i += 256) lh[i] = 0;
    __syncthreads();
    for (int i = t; i < cnt; i += 256) {
        int2 e = binned[base + i];
        eb[i] = e;
        atomicAdd(&lh[(e.x >> 17) & 127], 1);
    }
    __syncthreads();
    // exclusive scan of lh[0..NPB) by wave 0 (2 counters per lane)
    if (t < 64) {
        int loc[2]; int s = 0;
#pragma unroll
        for (int j = 0; j < 2; ++j) { loc[j] = lh[t * 2 + j]; s += loc[j]; }
        int inc = s;
        for (int d = 1; d < 64; d <<= 1) {
            int o = __shfl_up(inc, d, 64);
            if (t >= d) inc += o;
        }
        int ex = inc - s;
#pragma unroll
        for (int j = 0; j < 2; ++j) { cu[t * 2 + j] = ex; ex += loc[j]; }
    }
    __syncthreads();
    int node0 = b << 7;
    for (int i = t; i < NPB; i += 256) {
        int node = node0 + i;
        if (node < N) offsets[node] = base + cu[i];
    }
    if (b == NB - 1 && t == 0) offsets[N] = total;
    __syncthreads();
    for (int i = t; i < cnt; i += 256) {
        int2 e = eb[i];
        int d = (e.x >> 17) & 127;
        int pos = atomicAdd(&cu[d], 1);
        sedge[base + pos] = e;   // keep dl in payload
    }
}

// ---- MFMA bf16 GEMM: hidden = x@W + b ----------------------------------
__global__ __launch_bounds__(256) void gemm_proj_kernel(
        const float* __restrict__ x, const float* __restrict__ W,
        const float* __restrict__ b, const float* __restrict__ query,
        unsigned short* __restrict__ hbu, float* __restrict__ ain,
        float* __restrict__ aout, int N) {
    __shared__ unsigned short xs[64 * 136];
    __shared__ unsigned short wt[128 * 136];
    int t = threadIdx.x;
    int row0 = blockIdx.x * 64;

    {
        const float4* x4 = (const float4*)x;
#pragma unroll
        for (int i = 0; i < 8; ++i) {
            int f = t + i * 256;
            int row = f >> 5, c4 = f & 31;
            int gr = row0 + row;
            if (gr >= N) gr = N - 1;
            float4 v = x4[(size_t)gr * 32 + c4];
            unsigned int u0 = f2bf(v.x) | (f2bf(v.y) << 16);
            unsigned int u1 = f2bf(v.z) | (f2bf(v.w) << 16);
            *(uint2*)&xs[row * 136 + 4 * c4] = make_uint2(u0, u1);
        }
    }
    {
        const float4* W4 = (const float4*)W;
#pragma unroll
        for (int i = 0; i < 16; ++i) {
            int f = t + i * 256;
            int k = f & 127, c4 = f >> 7;
            float4 v = W4[k * 32 + c4];
            wt[(4 * c4 + 0) * 136 + k] = (unsigned short)f2bf(v.x);
            wt[(4 * c4 + 1) * 136 + k] = (unsigned short)f2bf(v.y);
            wt[(4 * c4 + 2) * 136 + k] = (unsigned short)f2bf(v.z);
            wt[(4 * c4 + 3) * 136 + k] = (unsigned short)f2bf(v.w);
        }
    }
    __syncthreads();

    int lane = t & 63, wv = t >> 6;
    int d = lane & 15, g = lane >> 4;
    int tbase = wv * 16;

    bf16x8 af[4];
#pragma unroll
    for (int s = 0; s < 4; ++s)
        af[s] = *(bf16x8*)&xs[(tbase + d) * 136 + s * 32 + g * 8];

    f32x4 acc[8];
#pragma unroll
    for (int c = 0; c < 8; ++c) acc[c] = (f32x4){0.f, 0.f, 0.f, 0.f};

#pragma unroll
    for (int c = 0; c < 8; ++c) {
#pragma unroll
        for (int s = 0; s < 4; ++s) {
            bf16x8 bf = *(bf16x8*)&wt[(d + 16 * c) * 136 + s * 32 + g * 8];
            acc[c] = __builtin_amdgcn_mfma_f32_16x16x32_bf16(af[s], bf, acc[c], 0, 0, 0);
        }
    }

    int rbase = row0 + tbase + g * 4;
#pragma unroll
    for (int c = 0; c < 8; ++c) {
        float bc = b[d + 16 * c];
        float2 q2 = *(const float2*)(query + c * 2 * DH + 2 * d);
#pragma unroll
        for (int j = 0; j < 4; ++j) {
            float v = acc[c][j] + bc;
            int row = rbase + j;
            if (row < N) hbu[(size_t)row * OD + d + 16 * c] = (unsigned short)f2bf(v);
            float pin = q2.x * v, pout = q2.y * v;
#pragma unroll
            for (int m = 1; m < 16; m <<= 1) {
                pin  += __shfl_xor(pin, m, 64);
                pout += __shfl_xor(pout, m, 64);
            }
            if (d == 0 && row < N) {
                ain[row * NH + c] = pin;
                aout[row * NH + c] = pout;
            }
        }
    }
}

// ---- edge attention: one thread per (node, head) ------------------------
// att layout: attB[idx * NH + h] (bf16). 8 h-threads of a node run in
// lockstep -> contiguous 16B stores; sedge loads broadcast. No atomics.
__global__ __launch_bounds__(256) void edgeatt_kernel(
        const int* __restrict__ offsets, const int2* __restrict__ sedge,
        const float* __restrict__ ain, const float* __restrict__ aout,
        unsigned short* __restrict__ attB, int* __restrict__ srcArr,
        float* __restrict__ scaleG, int N) {
    int id = blockIdx.x * blockDim.x + threadIdx.x;
    int n = id >> 3, h = id & 7;
    if (n >= N) return;
    int beg = offsets[n], end = offsets[n + 1];
    float ao = aout[n * NH + h];

    float sum = 0.0f;
    int i = beg;
    for (; i + 1 < end; i += 2) {
        int2 e0 = sedge[i];
        int2 e1 = sedge[i + 1];
        int s0 = e0.x & 0x1FFFF, s1 = e1.x & 0x1FFFF;
        float a0 = ain[s0 * NH + h];
        float a1 = ain[s1 * NH + h];
        a0 += ao; a0 = (a0 > 0.0f) ? a0 : 0.2f * a0;
        a1 += ao; a1 = (a1 > 0.0f) ? a1 : 0.2f * a1;
        float t0 = __expf(a0) * __int_as_float(e0.y);
        float t1 = __expf(a1) * __int_as_float(e1.y);
        attB[(size_t)i * NH + h] = (unsigned short)f2bf(t0);
        attB[(size_t)(i + 1) * NH + h] = (unsigned short)f2bf(t1);
        sum += t0 + t1;
        if (h == 0) { srcArr[i] = s0; srcArr[i + 1] = s1; }
    }
    if (i < end) {
        int2 e0 = sedge[i];
        int s0 = e0.x & 0x1FFFF;
        float a0 = ain[s0 * NH + h] + ao;
        a0 = (a0 > 0.0f) ? a0 : 0.2f * a0;
        float t0 = __expf(a0) * __int_as_float(e0.y);
        attB[(size_t)i * NH + h] = (unsigned short)f2bf(t0);
        sum += t0;
        if (h == 0) srcArr[i] = s0;
    }
    float c = (float)(end - beg);
    scaleG[n * NH + h] = 1.0f / ((sum / c + 1e-10f) * c);
}

// ---- aggregate: one wave per node, half-wave per edge group -------------
// lane = (half = l>>5, q = l&31). lane owns dims 4q..4q+3. head h = q>>2.
// 4 edges per half per iteration (8 per wave). att layout [idx*NH+h].
__global__ __launch_bounds__(256) void aggregate_kernel(
        const int* __restrict__ offsets, const int* __restrict__ srcArr,
        const unsigned short* __restrict__ attB, const float* __restrict__ scaleG,
        const uint2* __restrict__ hb2, float* __restrict__ out, int N) {
    int n = (blockIdx.x * blockDim.x + threadIdx.x) >> 6;
    int lane = threadIdx.x & 63;
    if (n >= N) return;
    int beg = offsets[n], end = offsets[n + 1];
    int half = lane >> 5, q = lane & 31;
    int h = q >> 2;

    float4 acc = make_float4(0.f, 0.f, 0.f, 0.f);
    for (int i = beg; i < end; i += 8) {
        int ib = i + 4 * half;          // this lane's 4 edges: ib..ib+3
        int s[4]; float a[4];
#pragma unroll
        for (int k = 0; k < 4; ++k) {
            s[k] = srcArr[ib + k] & 0x1FFFF;   // padded reads past end are mapped
            a[k] = (ib + k < end)
                 ? __uint_as_float((unsigned int)attB[(size_t)(ib + k) * NH + h] << 16)
                 : 0.0f;
        }
        uint2 w[4];
#pragma unroll
        for (int k = 0; k < 4; ++k)
            w[k] = hb2[(size_t)s[k] * 32 + q];
#pragma unroll
        for (int k = 0; k < 4; ++k) {
            acc.x += a[k] * __uint_as_float(w[k].x << 16);
            acc.y += a[k] * __uint_as_float(w[k].x & 0xffff0000u);
            acc.z += a[k] * __uint_as_float(w[k].y << 16);
            acc.w += a[k] * __uint_as_float(w[k].y & 0xffff0000u);
        }
    }
    acc.x += __shfl_xor(acc.x, 32, 64);
    acc.y += __shfl_xor(acc.y, 32, 64);
    acc.z += __shfl_xor(acc.z, 32, 64);
    acc.w += __shfl_xor(acc.w, 32, 64);
    if (half == 0) {
        float sc = scaleG[n * NH + h];
        float4 o;
        o.x = acc.x * sc; o.y = acc.y * sc; o.z = acc.z * sc; o.w = acc.w * sc;
        o.x = o.x > 0.f ? o.x : 0.f;
        o.y = o.y > 0.f ? o.y : 0.f;
        o.z = o.z > 0.f ? o.z : 0.f;
        o.w = o.w > 0.f ? o.w : 0.f;
        *(float4*)(out + (size_t)n * OD + 4 * q) = o;
    }
}

extern "C" void kernel_launch(void* const* d_in, const int* in_sizes, int n_in,
                              void* d_out, int out_size, void* d_ws, size_t ws_size,
                              hipStream_t stream) {
    const float* x     = (const float*)d_in[0];
    const int2*  el    = (const int2*)d_in[1];
    const float* ew    = (const float*)d_in[2];
    const float* W     = (const float*)d_in[3];
    const float* b     = (const float*)d_in[4];
    const float* query = (const float*)d_in[5];
    float* out = (float*)d_out;

    int N = in_sizes[0] / OD;
    int E = in_sizes[1] / 2;
    int total = E + N;
    int NB = (N + NPB - 1) / NPB;            // bins
    int CH = (total + NCH - 1) / NCH;        // edges per chunk
    int n2 = NB * NCH;                        // count-matrix size

    char* ws = (char*)d_ws;
    size_t off = 0;
    auto take = [&](size_t bytes) -> void* {
        void* p = ws + off;
        off = (off + bytes + 255) & ~(size_t)255;
        return p;
    };
    unsigned int* hb = (unsigned int*)take((size_t)N * 64 * 4);  // bf16x2 hidden
    float* ain     = (float*)take((size_t)N * NH * 4);
    float* aout    = (float*)take((size_t)N * NH * 4);
    int*   cnt     = (int*)take((size_t)n2 * 4);
    int*   S       = (int*)take((size_t)(n2 + 1) * 4);
    int*   offsets = (int*)take((size_t)(N + 1) * 4);
    int*   bsums   = (int*)take(4096);
    int2*  binned  = (int2*)take((size_t)total * 8);
    int2*  sedge   = (int2*)take((size_t)total * 8);
    unsigned short* attB = (unsigned short*)take(((size_t)(total + 8) * NH) * 2);
    // srcArr + scaleG alias the (dead-after-binsort) binned buffer
    int*   srcArr  = (int*)binned;
    float* scaleG  = (float*)((char*)binned + ((size_t)total + 16) * 4);

    binhist_kernel<<<NCH, 256, 0, stream>>>(el, cnt, E, total, CH, NB);
    int nb = (n2 + 1023) / 1024;
    scan1_kernel<<<nb, 1024, 0, stream>>>(cnt, S, bsums, n2);
    scan2_kernel<<<1, 1024, 0, stream>>>(bsums, nb);
    scan3b_kernel<<<nb, 1024, 0, stream>>>(S, bsums, cnt, n2);
    binscatter_kernel<<<NCH, 256, 0, stream>>>(el, ew, S, binned, E, total, CH, NB);
    binsort_kernel<<<NB, 256, 0, stream>>>(binned, S, sedge, offsets, N, NB, total);
    gemm_proj_kernel<<<(N + 63) / 64, 256, 0, stream>>>(
        x, W, b, query, (unsigned short*)hb, ain, aout, N);
    edgeatt_kernel<<<((size_t)N * NH + 255) / 256, 256, 0, stream>>>(
        offsets, sedge, ain, aout, attB, srcArr, scaleG, N);
    aggregate_kernel<<<((size_t)N * 64 + 255) / 256, 256, 0, stream>>>(
        offsets, srcArr, attB, scaleG, (const uint2*)hb, out, N);
}